// Round 1
// baseline (121.901 us; speedup 1.0000x reference)
//
#include <hip/hip_runtime.h>
#include <hip/hip_bf16.h>

typedef __bf16 bf16x4 __attribute__((ext_vector_type(4)));
typedef __bf16 bf16x8 __attribute__((ext_vector_type(8)));
typedef float f32x4 __attribute__((ext_vector_type(4)));

#define N_PIX 4608      // 2*48*48
#define D_MODEL 512
#define QKV_N 1536

// async global->LDS, 16B per lane. LDS dest is wave-uniform base; HW adds lane*16.
__device__ __forceinline__ void gload_lds16(const void* g, void* l) {
  __builtin_amdgcn_global_load_lds(
      (const __attribute__((address_space(1))) unsigned int*)g,
      (__attribute__((address_space(3))) unsigned int*)l, 16, 0, 0);
}

// ---------------- fused prep: x->bf16 + both weight transposes ----------------
// blocks [0,2304): x convert; [2304,3072): w_qkv^T (q-scale folded); [3072,3328): w_out^T
__global__ __launch_bounds__(256) void prep_kernel(
    const float* __restrict__ x, const float* __restrict__ wq,
    const float* __restrict__ wo, __bf16* __restrict__ xbf,
    __bf16* __restrict__ wqT, __bf16* __restrict__ woT) {
  int b = blockIdx.x, tid = threadIdx.x;
  if (b < 2304) {
    int i = b * 1024 + tid * 4;
    float4 v = *(const float4*)&x[i];
    bf16x4 o = {(__bf16)v.x, (__bf16)v.y, (__bf16)v.z, (__bf16)v.w};
    *(bf16x4*)&xbf[i] = o;
    return;
  }
  __shared__ float tile[32][33];
  const float* src; __bf16* dst; int R, C, bx, by;
  bool is_wq;
  if (b < 3072) {
    int t = b - 2304; src = wq; dst = wqT; R = 512; C = 1536;
    bx = (t % 48) * 32; by = (t / 48) * 32; is_wq = true;
  } else {
    int t = b - 3072; src = wo; dst = woT; R = 512; C = 512;
    bx = (t & 15) * 32; by = (t >> 4) * 32; is_wq = false;
  }
  int tx = tid & 31, ty = tid >> 5;
#pragma unroll
  for (int i = 0; i < 32; i += 8)
    tile[ty + i][tx] = src[(by + ty + i) * C + bx + tx];
  __syncthreads();
#pragma unroll
  for (int i = 0; i < 32; i += 8) {
    int outrow = bx + ty + i;
    float v = tile[tx][ty + i];
    if (is_wq && outrow < 512) v *= 0.125f;  // fold q/sqrt(D_HEAD) into weights
    dst[outrow * R + by + tx] = (__bf16)v;
  }
}

// ---------------- bf16 MFMA GEMM, templated tile, dbuf global_load_lds --------
// C[MxN] = A[MxK] * Bt[NxK]^T. Block tile BM x BN, BK=32, 4 waves (2x2),
// wave tile (BM/2) x (BN/2). 128x128 = m97 geometry: 16 MFMA per wave-k-step,
// 512 B LDS-read per MFMA, 32 KB LDS -> ~3 blocks/CU resident.
// Fragment layouts (verified m89): A[m=lane&15][k=quad*8+j]; Bt[n=lane&15][k=quad*8+j];
// C/D: row=quad*4+reg, col=lane&15.
template <int BM, int BN>
__global__ __launch_bounds__(256) void gemm_kernel(
    const __bf16* __restrict__ A, const __bf16* __restrict__ Bt,
    void* __restrict__ C, int M, int N, int K, int c_is_f32) {
  constexpr int MT = BM / 32;      // MFMA row-tiles per wave
  constexpr int NT = BN / 32;      // MFMA col-tiles per wave
  constexpr int AR = BM / 4;       // A rows staged per wave (16 or 32)
  constexpr int BR = BN / 4;       // B rows staged per wave (16 or 32)
  __shared__ __bf16 sA[2][BM * 32];
  __shared__ __bf16 sB[2][BN * 32];
  int tid = threadIdx.x;
  int wv = tid >> 6, lane = tid & 63;
  int quad = lane >> 4, r16 = lane & 15;
  int m0 = blockIdx.y * BM, n0 = blockIdx.x * BN;

  int rA = lane >> 2;           // 0..15
  int kc = (lane & 3) * 8;      // 0,8,16,24
  const __bf16* Ag0 = A + (long)(m0 + wv * AR + rA) * K + kc;
  const __bf16* Bg0 = Bt + (long)(n0 + wv * BR + rA) * K + kc;

  int mw = (wv & 1) * (BM / 2), nw = (wv >> 1) * (BN / 2);

  f32x4 acc[MT][NT];
#pragma unroll
  for (int mt = 0; mt < MT; ++mt)
#pragma unroll
    for (int nt = 0; nt < NT; ++nt) acc[mt][nt] = f32x4{0.f, 0.f, 0.f, 0.f};

  auto stage = [&](int buf, int k0) {
    gload_lds16(Ag0 + k0, &sA[buf][(wv * AR) * 32]);
    if (AR == 32)
      gload_lds16(Ag0 + (long)16 * K + k0, &sA[buf][(wv * AR + 16) * 32]);
    gload_lds16(Bg0 + k0, &sB[buf][(wv * BR) * 32]);
    if (BR == 32)
      gload_lds16(Bg0 + (long)16 * K + k0, &sB[buf][(wv * BR + 16) * 32]);
  };

  stage(0, 0);
  int cur = 0;
  for (int k0 = 0; k0 < K; k0 += 32) {
    __syncthreads();
    if (k0 + 32 < K) stage(cur ^ 1, k0 + 32);
    bf16x8 af[MT], bfr[NT];
#pragma unroll
    for (int mt = 0; mt < MT; ++mt)
      af[mt] = *(const bf16x8*)&sA[cur][(mw + mt * 16 + r16) * 32 + quad * 8];
#pragma unroll
    for (int nt = 0; nt < NT; ++nt)
      bfr[nt] = *(const bf16x8*)&sB[cur][(nw + nt * 16 + r16) * 32 + quad * 8];
#pragma unroll
    for (int mt = 0; mt < MT; ++mt)
#pragma unroll
      for (int nt = 0; nt < NT; ++nt)
        acc[mt][nt] = __builtin_amdgcn_mfma_f32_16x16x32_bf16(af[mt], bfr[nt], acc[mt][nt], 0, 0, 0);
    cur ^= 1;
  }

  __bf16* Cb = (__bf16*)C;
  float* Cf = (float*)C;
#pragma unroll
  for (int mt = 0; mt < MT; ++mt)
#pragma unroll
    for (int r = 0; r < 4; ++r) {
      int row = m0 + mw + mt * 16 + quad * 4 + r;
#pragma unroll
      for (int nt = 0; nt < NT; ++nt) {
        int col = n0 + nw + nt * 16 + r16;
        float v = acc[mt][nt][r];
        if (c_is_f32) Cf[(long)row * N + col] = v;
        else          Cb[(long)row * N + col] = (__bf16)v;
      }
    }
}

// ---------------- neighborhood attention, LDS-tiled, 512 threads ----------------
// Block = 8x8 query tile x 1 head, 8 waves. Stage 14x14 K/V halo (64ch bf16) in LDS.
// 8 lanes per query, each owns 8 channels. Row stride 72 elems (144 B).
// q-scale is pre-folded into w_qkv columns (prep).
#define KSTR 72
__global__ __launch_bounds__(512) void natten_attn_kernel(
    const __bf16* __restrict__ qkv, __bf16* __restrict__ o) {
  __shared__ __bf16 sK[196 * KSTR];
  __shared__ __bf16 sV[196 * KSTR];
  int tid = threadIdx.x;
  int bid = blockIdx.x;                 // 0..575
  int nB = bid / 288;
  int rem = bid - nB * 288;
  int head = rem / 36;
  int tile = rem - head * 36;
  int tr = tile / 6, tc = tile - tr * 6;
  int r0 = tr * 8, c0 = tc * 8;
  int loH = r0 - 3; loH = loH < 0 ? 0 : (loH > 41 ? 41 : loH);
  int loW = c0 - 3; loW = loW < 0 ? 0 : (loW > 41 ? 41 : loW);

  for (int j = tid; j < 196 * 8; j += 512) {
    int rowi = j >> 3, ch = j & 7;
    int rr = rowi / 14, cc = rowi - rr * 14;
    int hh = loH + rr; hh = hh > 47 ? 47 : hh;
    int wp = loW + cc; wp = wp > 47 ? 47 : wp;
    long base = (long)(nB * 2304 + hh * 48 + wp) * QKV_N + head * 64 + ch * 8;
    *(uint4*)&sK[rowi * KSTR + ch * 8] = *(const uint4*)&qkv[base + 512];
    *(uint4*)&sV[rowi * KSTR + ch * 8] = *(const uint4*)&qkv[base + 1024];
  }
  __syncthreads();

  int q = tid >> 3, s = tid & 7;        // 64 queries x 8 channel-slices
  int qr = q >> 3, qc = q & 7;
  int h = r0 + qr, w = c0 + qc;
  int pix = nB * 2304 + h * 48 + w;
  int hs = h - 3; hs = hs < 0 ? 0 : (hs > 41 ? 41 : hs); hs -= loH;
  int ws = w - 3; ws = ws < 0 ? 0 : (ws > 41 ? 41 : ws); ws -= loW;
  int base = (hs * 14 + ws) * KSTR + s * 8;

  bf16x8 q0 = *(const bf16x8*)&qkv[(long)pix * QKV_N + head * 64 + s * 8];
  float qf[8];
#pragma unroll
  for (int t = 0; t < 8; ++t) qf[t] = (float)q0[t];

  float lg[49];
#pragma unroll
  for (int j = 0; j < 49; ++j) {
    int a = j / 7, b = j % 7;
    bf16x8 k0 = *(const bf16x8*)&sK[base + (a * 14 + b) * KSTR];
    float acc = 0.f;
#pragma unroll
    for (int t = 0; t < 8; ++t) acc = fmaf(qf[t], (float)k0[t], acc);
    acc += __shfl_xor(acc, 1);
    acc += __shfl_xor(acc, 2);
    acc += __shfl_xor(acc, 4);
    lg[j] = acc;
  }

  float mx = lg[0];
#pragma unroll
  for (int j = 1; j < 49; ++j) mx = fmaxf(mx, lg[j]);
  float sm = 0.f;
#pragma unroll
  for (int j = 0; j < 49; ++j) { lg[j] = __expf(lg[j] - mx); sm += lg[j]; }
  float inv = 1.f / sm;

  float ov[8];
#pragma unroll
  for (int t = 0; t < 8; ++t) ov[t] = 0.f;
#pragma unroll
  for (int j = 0; j < 49; ++j) {
    int a = j / 7, b = j % 7;
    float pj = lg[j] * inv;
    bf16x8 v0 = *(const bf16x8*)&sV[base + (a * 14 + b) * KSTR];
#pragma unroll
    for (int t = 0; t < 8; ++t) ov[t] = fmaf(pj, (float)v0[t], ov[t]);
  }

  bf16x8 o0;
#pragma unroll
  for (int t = 0; t < 8; ++t) o0[t] = (__bf16)ov[t];
  *(bf16x8*)&o[(long)pix * D_MODEL + head * 64 + s * 8] = o0;
}

// ---------------- launch ----------------

extern "C" void kernel_launch(void* const* d_in, const int* in_sizes, int n_in,
                              void* d_out, int out_size, void* d_ws, size_t ws_size,
                              hipStream_t stream) {
  const float* x = (const float*)d_in[0];      // (2,48,48,512)
  const float* w_qkv = (const float*)d_in[1];  // (512,1536)
  const float* w_out = (const float*)d_in[2];  // (512,512)
  float* out = (float*)d_out;                  // (2,48,48,512)

  __bf16* ws = (__bf16*)d_ws;
  __bf16* xbf   = ws;                                   // 4608*512
  __bf16* wqkvT = xbf + N_PIX * D_MODEL;                // 1536*512
  __bf16* woutT = wqkvT + QKV_N * D_MODEL;              // 512*512
  __bf16* qkvb  = woutT + D_MODEL * D_MODEL;            // 4608*1536
  __bf16* obf   = qkvb + N_PIX * QKV_N;                 // 4608*512

  // prep: x->bf16 (2304 blocks) + w_qkv^T scaled (768) + w_out^T (256)
  prep_kernel<<<3328, 256, 0, stream>>>(x, w_qkv, w_out, xbf, wqkvT, woutT);
  // qkv = xbf @ w_qkv -> bf16 (4608 x 1536); 128x128 tile -> 12x36=432 blocks (1.7/CU, ~3 resident)
  gemm_kernel<128, 128><<<dim3(QKV_N / 128, N_PIX / 128), 256, 0, stream>>>(
      xbf, wqkvT, qkvb, N_PIX, QKV_N, D_MODEL, 0);
  // attention -> obf (4608 x 512)
  natten_attn_kernel<<<576, 512, 0, stream>>>(qkvb, obf);
  // out = obf @ w_out -> fp32; 64x128 tile -> 4x72=288 blocks (2x FLOP/drain vs 64x64)
  gemm_kernel<64, 128><<<dim3(D_MODEL / 128, N_PIX / 64), 256, 0, stream>>>(
      obf, woutT, out, N_PIX, D_MODEL, D_MODEL, 1);
}

// Round 2
// 115.224 us; speedup vs baseline: 1.0580x; 1.0580x over previous
//
#include <hip/hip_runtime.h>
#include <hip/hip_bf16.h>

typedef __bf16 bf16x4 __attribute__((ext_vector_type(4)));
typedef __bf16 bf16x8 __attribute__((ext_vector_type(8)));
typedef float f32x4 __attribute__((ext_vector_type(4)));

#define N_PIX 4608      // 2*48*48
#define D_MODEL 512
#define QKV_N 1536

// async global->LDS, 16B per lane. LDS dest is wave-uniform base; HW adds lane*16.
__device__ __forceinline__ void gload_lds16(const void* g, void* l) {
  __builtin_amdgcn_global_load_lds(
      (const __attribute__((address_space(1))) unsigned int*)g,
      (__attribute__((address_space(3))) unsigned int*)l, 16, 0, 0);
}

// ---------------- fused prep: x->bf16 + both weight transposes ----------------
// blocks [0,2304): x convert; [2304,3072): w_qkv^T (q-scale folded); [3072,3328): w_out^T
__global__ __launch_bounds__(256) void prep_kernel(
    const float* __restrict__ x, const float* __restrict__ wq,
    const float* __restrict__ wo, __bf16* __restrict__ xbf,
    __bf16* __restrict__ wqT, __bf16* __restrict__ woT) {
  int b = blockIdx.x, tid = threadIdx.x;
  if (b < 2304) {
    int i = b * 1024 + tid * 4;
    float4 v = *(const float4*)&x[i];
    bf16x4 o = {(__bf16)v.x, (__bf16)v.y, (__bf16)v.z, (__bf16)v.w};
    *(bf16x4*)&xbf[i] = o;
    return;
  }
  __shared__ float tile[32][33];
  const float* src; __bf16* dst; int R, C, bx, by;
  bool is_wq;
  if (b < 3072) {
    int t = b - 2304; src = wq; dst = wqT; R = 512; C = 1536;
    bx = (t % 48) * 32; by = (t / 48) * 32; is_wq = true;
  } else {
    int t = b - 3072; src = wo; dst = woT; R = 512; C = 512;
    bx = (t & 15) * 32; by = (t >> 4) * 32; is_wq = false;
  }
  int tx = tid & 31, ty = tid >> 5;
#pragma unroll
  for (int i = 0; i < 32; i += 8)
    tile[ty + i][tx] = src[(by + ty + i) * C + bx + tx];
  __syncthreads();
#pragma unroll
  for (int i = 0; i < 32; i += 8) {
    int outrow = bx + ty + i;
    float v = tile[tx][ty + i];
    if (is_wq && outrow < 512) v *= 0.125f;  // fold q/sqrt(D_HEAD) into weights
    dst[outrow * R + by + tx] = (__bf16)v;
  }
}

// ---------------- bf16 MFMA GEMM, templated tile, dbuf global_load_lds --------
// C[MxN] = A[MxK] * Bt[NxK]^T. Block tile BM x BN, BK=32, 4 waves (2x2).
// Fragment layouts (verified m89): A[m=lane&15][k=quad*8+j]; Bt[n=lane&15][k=quad*8+j];
// C/D: row=quad*4+reg, col=lane&15.
template <int BM, int BN>
__global__ __launch_bounds__(256) void gemm_kernel(
    const __bf16* __restrict__ A, const __bf16* __restrict__ Bt,
    void* __restrict__ C, int M, int N, int K, int c_is_f32) {
  constexpr int MT = BM / 32;      // MFMA row-tiles per wave
  constexpr int NT = BN / 32;      // MFMA col-tiles per wave
  constexpr int AR = BM / 4;       // A rows staged per wave (16 or 32)
  constexpr int BR = BN / 4;       // B rows staged per wave (16 or 32)
  __shared__ __bf16 sA[2][BM * 32];
  __shared__ __bf16 sB[2][BN * 32];
  int tid = threadIdx.x;
  int wv = tid >> 6, lane = tid & 63;
  int quad = lane >> 4, r16 = lane & 15;
  int m0 = blockIdx.y * BM, n0 = blockIdx.x * BN;

  int rA = lane >> 2;           // 0..15
  int kc = (lane & 3) * 8;      // 0,8,16,24
  const __bf16* Ag0 = A + (long)(m0 + wv * AR + rA) * K + kc;
  const __bf16* Bg0 = Bt + (long)(n0 + wv * BR + rA) * K + kc;

  int mw = (wv & 1) * (BM / 2), nw = (wv >> 1) * (BN / 2);

  f32x4 acc[MT][NT];
#pragma unroll
  for (int mt = 0; mt < MT; ++mt)
#pragma unroll
    for (int nt = 0; nt < NT; ++nt) acc[mt][nt] = f32x4{0.f, 0.f, 0.f, 0.f};

  auto stage = [&](int buf, int k0) {
    gload_lds16(Ag0 + k0, &sA[buf][(wv * AR) * 32]);
    if (AR == 32)
      gload_lds16(Ag0 + (long)16 * K + k0, &sA[buf][(wv * AR + 16) * 32]);
    gload_lds16(Bg0 + k0, &sB[buf][(wv * BR) * 32]);
    if (BR == 32)
      gload_lds16(Bg0 + (long)16 * K + k0, &sB[buf][(wv * BR + 16) * 32]);
  };

  stage(0, 0);
  int cur = 0;
  for (int k0 = 0; k0 < K; k0 += 32) {
    __syncthreads();
    if (k0 + 32 < K) stage(cur ^ 1, k0 + 32);
    bf16x8 af[MT], bfr[NT];
#pragma unroll
    for (int mt = 0; mt < MT; ++mt)
      af[mt] = *(const bf16x8*)&sA[cur][(mw + mt * 16 + r16) * 32 + quad * 8];
#pragma unroll
    for (int nt = 0; nt < NT; ++nt)
      bfr[nt] = *(const bf16x8*)&sB[cur][(nw + nt * 16 + r16) * 32 + quad * 8];
#pragma unroll
    for (int mt = 0; mt < MT; ++mt)
#pragma unroll
      for (int nt = 0; nt < NT; ++nt)
        acc[mt][nt] = __builtin_amdgcn_mfma_f32_16x16x32_bf16(af[mt], bfr[nt], acc[mt][nt], 0, 0, 0);
    cur ^= 1;
  }

  __bf16* Cb = (__bf16*)C;
  float* Cf = (float*)C;
#pragma unroll
  for (int mt = 0; mt < MT; ++mt)
#pragma unroll
    for (int r = 0; r < 4; ++r) {
      int row = m0 + mw + mt * 16 + quad * 4 + r;
#pragma unroll
      for (int nt = 0; nt < NT; ++nt) {
        int col = n0 + nw + nt * 16 + r16;
        float v = acc[mt][nt][r];
        if (c_is_f32) Cf[(long)row * N + col] = v;
        else          Cb[(long)row * N + col] = (__bf16)v;
      }
    }
}

// ---------------- neighborhood attention, MFMA over padded 224-pos halo ----------
// Block = 8x8 query tile x 1 head, 4 waves (256 thr). Halo 14x14=196 pos, padded
// to NP=224 (14 n-tiles of 16); invalid (pos,query) pairs masked to -1e30 pre-softmax.
// QK: D[q][pos] = Q[q][k] * K[pos][k]  (A=Q rows, Bt=K rows, both LDS row-major 128B,
//     XOR-swizzled byte^=((row&7)<<4); staged via gload_lds16 w/ pre-swizzled source).
// PV: D[q][ch]  = P[q][pos] * VT[ch][pos] (P reuses dead K buffer; VT is reg-scatter
//     transposed at staging; both 512B rows, same XOR swizzle on write AND read).
// Wave wv owns query m-tile wv for BOTH gemms -> softmax + inv stay lane-local.
__global__ __launch_bounds__(256) void natten_attn_kernel(
    const __bf16* __restrict__ qkv, __bf16* __restrict__ o) {
  __shared__ __bf16 sKP[16384];   // 32KB: K[224 x 128B, swz] -> reused as P[64 x 512B, swz]
  __shared__ __bf16 sVT[16384];   // 32KB: V^T[64ch x 512B, swz]
  __shared__ __bf16 sQ[4096];     // 8KB:  Q[64 x 128B, swz]
  char* kB = (char*)sKP;
  char* vB = (char*)sVT;
  char* qB = (char*)sQ;

  int tid = threadIdx.x;
  int lane = tid & 63, wv = tid >> 6;
  int quad = lane >> 4, r16 = lane & 15;
  int bid = blockIdx.x;                 // 0..575
  int nB = bid / 288;
  int rem = bid - nB * 288;
  int head = rem / 36;
  int tile = rem - head * 36;
  int tr = tile / 6, tc = tile - tr * 6;
  int r0 = tr * 8, c0 = tc * 8;
  int loH = r0 - 3; loH = loH < 0 ? 0 : (loH > 41 ? 41 : loH);
  int loW = c0 - 3; loW = loW < 0 ? 0 : (loW > 41 ? 41 : loW);
  long hb = (long)head * 64;

  // ---- stage K (28 groups of 8 rows) + Q (8 groups) via gload_lds16, pre-swizzled src
  {
    int rl = lane >> 3, cc = lane & 7;   // row-in-group, dest 16B chunk
#pragma unroll
    for (int it = 0; it < 7; ++it) {
      int g = wv * 7 + it;
      int row = g * 8 + rl;
      int pos = row > 195 ? 195 : row;
      int pr = pos / 14, pc = pos - pr * 14;
      int hh = loH + pr; hh = hh > 47 ? 47 : hh;
      int wp = loW + pc; wp = wp > 47 ? 47 : wp;
      int csrc = cc ^ (row & 7);         // inverse-swizzled source chunk
      const __bf16* src = qkv + (long)(nB * 2304 + hh * 48 + wp) * QKV_N + 512 + hb + csrc * 8;
      gload_lds16(src, kB + g * 1024);
    }
#pragma unroll
    for (int it = 0; it < 2; ++it) {
      int g = wv * 2 + it;
      int row = g * 8 + rl;              // query index 0..63
      int csrc = cc ^ (row & 7);
      int pix = nB * 2304 + (r0 + (row >> 3)) * 48 + c0 + (row & 7);
      const __bf16* src = qkv + (long)pix * QKV_N + hb + csrc * 8;
      gload_lds16(src, qB + g * 1024);
    }
  }
  // ---- stage V^T via reg scatter: V[pos][ch] -> sVT[ch][pos], swizzled write
#pragma unroll
  for (int it = 0; it < 7; ++it) {
    int idx = tid + it * 256;            // 0..1791 = 224 pos x 8 chunks
    int pos = idx >> 3, cb = idx & 7;
    int pp = pos > 195 ? 195 : pos;
    int pr = pp / 14, pc = pp - pr * 14;
    int hh = loH + pr; hh = hh > 47 ? 47 : hh;
    int wp = loW + pc; wp = wp > 47 ? 47 : wp;
    bf16x8 v = *(const bf16x8*)(qkv + (long)(nB * 2304 + hh * 48 + wp) * QKV_N + 1024 + hb + cb * 8);
#pragma unroll
    for (int i = 0; i < 8; ++i) {
      int ch = cb * 8 + i;
      *(__bf16*)(vB + ch * 512 + ((2 * pos) ^ ((ch & 7) << 4))) = v[i];
    }
  }
  __syncthreads();

  // ---- QK^T: wave wv = query m-tile wv x 14 pos n-tiles, K=64 (2 ksteps)
  int rowq = wv * 16 + r16;
  int swq = (rowq & 7) << 4;
  bf16x8 aq0 = *(const bf16x8*)(qB + rowq * 128 + ((quad * 16) ^ swq));
  bf16x8 aq1 = *(const bf16x8*)(qB + rowq * 128 + ((64 + quad * 16) ^ swq));
  f32x4 acc[14];
#pragma unroll
  for (int nt = 0; nt < 14; ++nt) acc[nt] = f32x4{0.f, 0.f, 0.f, 0.f};
#pragma unroll
  for (int nt = 0; nt < 14; ++nt) {
    int rk = nt * 16 + r16;
    int swk = (rk & 7) << 4;
    bf16x8 b0 = *(const bf16x8*)(kB + rk * 128 + ((quad * 16) ^ swk));
    bf16x8 b1 = *(const bf16x8*)(kB + rk * 128 + ((64 + quad * 16) ^ swk));
    acc[nt] = __builtin_amdgcn_mfma_f32_16x16x32_bf16(aq0, b0, acc[nt], 0, 0, 0);
    acc[nt] = __builtin_amdgcn_mfma_f32_16x16x32_bf16(aq1, b1, acc[nt], 0, 0, 0);
  }

  // ---- mask + softmax. Lane holds queries quad*4+r (r=0..3), positions nt*16+r16.
  int hs[4], wsX[4];
#pragma unroll
  for (int r = 0; r < 4; ++r) {
    int q = wv * 16 + quad * 4 + r;
    int h = r0 + (q >> 3), w = c0 + (q & 7);
    int a = h - 3; a = a < 0 ? 0 : (a > 41 ? 41 : a);
    int b = w - 3; b = b < 0 ? 0 : (b > 41 ? 41 : b);
    hs[r] = a - loH; wsX[r] = b - loW;
  }
  {
    int pr = r16 >= 14 ? 1 : 0;
    int pc = r16 - pr * 14;
#pragma unroll
    for (int nt = 0; nt < 14; ++nt) {
      bool pv = (nt * 16 + r16) < 196;
#pragma unroll
      for (int r = 0; r < 4; ++r) {
        bool ok = pv && (unsigned)(pr - hs[r]) <= 6u && (unsigned)(pc - wsX[r]) <= 6u;
        acc[nt][r] = ok ? acc[nt][r] : -1e30f;
      }
      pc += 2; pr += 1;                 // pos += 16 == (+1 row, +2 cols) in 14-wide halo
      if (pc >= 14) { pc -= 14; pr += 1; }
    }
  }
  float inv[4];
#pragma unroll
  for (int r = 0; r < 4; ++r) {
    float m = acc[0][r];
#pragma unroll
    for (int nt = 1; nt < 14; ++nt) m = fmaxf(m, acc[nt][r]);
    m = fmaxf(m, __shfl_xor(m, 1));
    m = fmaxf(m, __shfl_xor(m, 2));
    m = fmaxf(m, __shfl_xor(m, 4));
    m = fmaxf(m, __shfl_xor(m, 8));
    float s = 0.f;
#pragma unroll
    for (int nt = 0; nt < 14; ++nt) { float e = __expf(acc[nt][r] - m); acc[nt][r] = e; s += e; }
    s += __shfl_xor(s, 1);
    s += __shfl_xor(s, 2);
    s += __shfl_xor(s, 4);
    s += __shfl_xor(s, 8);
    inv[r] = 1.f / s;
  }
  __syncthreads();   // all waves done reading sKP before it becomes P

  // ---- write P (bf16, unnormalized) into sKP as [64 q][512B, swz]
#pragma unroll
  for (int r = 0; r < 4; ++r) {
    int q = wv * 16 + quad * 4 + r;
    char* rowp = kB + q * 512;
    int sw = (q & 7) << 4;
#pragma unroll
    for (int nt = 0; nt < 14; ++nt) {
      int pos = nt * 16 + r16;
      *(__bf16*)(rowp + ((2 * pos) ^ sw)) = (__bf16)acc[nt][r];
    }
  }
  __syncthreads();

  // ---- PV: wave wv = query m-tile wv x 4 ch n-tiles, K=224 (7 ksteps)
  f32x4 acc2[4];
#pragma unroll
  for (int nt = 0; nt < 4; ++nt) acc2[nt] = f32x4{0.f, 0.f, 0.f, 0.f};
#pragma unroll
  for (int ks = 0; ks < 7; ++ks) {
    bf16x8 ap = *(const bf16x8*)(kB + rowq * 512 + ((ks * 64 + quad * 16) ^ swq));
#pragma unroll
    for (int nt = 0; nt < 4; ++nt) {
      int rc = nt * 16 + r16;
      bf16x8 bv = *(const bf16x8*)(vB + rc * 512 + ((ks * 64 + quad * 16) ^ ((rc & 7) << 4)));
      acc2[nt] = __builtin_amdgcn_mfma_f32_16x16x32_bf16(ap, bv, acc2[nt], 0, 0, 0);
    }
  }

  // ---- epilogue: normalize and store
#pragma unroll
  for (int r = 0; r < 4; ++r) {
    int q = wv * 16 + quad * 4 + r;
    long pix = nB * 2304 + (long)(r0 + (q >> 3)) * 48 + c0 + (q & 7);
    __bf16* op = o + pix * D_MODEL + hb;
    float iv = inv[r];
#pragma unroll
    for (int nt = 0; nt < 4; ++nt)
      op[nt * 16 + r16] = (__bf16)(acc2[nt][r] * iv);
  }
}

// ---------------- launch ----------------

extern "C" void kernel_launch(void* const* d_in, const int* in_sizes, int n_in,
                              void* d_out, int out_size, void* d_ws, size_t ws_size,
                              hipStream_t stream) {
  const float* x = (const float*)d_in[0];      // (2,48,48,512)
  const float* w_qkv = (const float*)d_in[1];  // (512,1536)
  const float* w_out = (const float*)d_in[2];  // (512,512)
  float* out = (float*)d_out;                  // (2,48,48,512)

  __bf16* ws = (__bf16*)d_ws;
  __bf16* xbf   = ws;                                   // 4608*512
  __bf16* wqkvT = xbf + N_PIX * D_MODEL;                // 1536*512
  __bf16* woutT = wqkvT + QKV_N * D_MODEL;              // 512*512
  __bf16* qkvb  = woutT + D_MODEL * D_MODEL;            // 4608*1536
  __bf16* obf   = qkvb + N_PIX * QKV_N;                 // 4608*512

  // prep: x->bf16 (2304 blocks) + w_qkv^T scaled (768) + w_out^T (256)
  prep_kernel<<<3328, 256, 0, stream>>>(x, w_qkv, w_out, xbf, wqkvT, woutT);
  // qkv = xbf @ w_qkv -> bf16 (4608 x 1536)
  gemm_kernel<128, 128><<<dim3(QKV_N / 128, N_PIX / 128), 256, 0, stream>>>(
      xbf, wqkvT, qkvb, N_PIX, QKV_N, D_MODEL, 0);
  // attention -> obf (4608 x 512), MFMA formulation
  natten_attn_kernel<<<576, 256, 0, stream>>>(qkvb, obf);
  // out = obf @ w_out -> fp32
  gemm_kernel<64, 128><<<dim3(D_MODEL / 128, N_PIX / 64), 256, 0, stream>>>(
      obf, woutT, out, N_PIX, D_MODEL, D_MODEL, 1);
}

// Round 3
// 112.011 us; speedup vs baseline: 1.0883x; 1.0287x over previous
//
#include <hip/hip_runtime.h>
#include <hip/hip_bf16.h>

typedef __bf16 bf16x4 __attribute__((ext_vector_type(4)));
typedef __bf16 bf16x8 __attribute__((ext_vector_type(8)));
typedef float f32x4 __attribute__((ext_vector_type(4)));

#define N_PIX 4608      // 2*48*48
#define D_MODEL 512
#define QKV_N 1536

// async global->LDS, 16B per lane. LDS dest is wave-uniform base; HW adds lane*16.
__device__ __forceinline__ void gload_lds16(const void* g, void* l) {
  __builtin_amdgcn_global_load_lds(
      (const __attribute__((address_space(1))) unsigned int*)g,
      (__attribute__((address_space(3))) unsigned int*)l, 16, 0, 0);
}

// ---------------- fused prep: x->bf16 + both weight transposes ----------------
// blocks [0,2304): x convert; [2304,3072): w_qkv^T (q-scale folded); [3072,3328): w_out^T
__global__ __launch_bounds__(256) void prep_kernel(
    const float* __restrict__ x, const float* __restrict__ wq,
    const float* __restrict__ wo, __bf16* __restrict__ xbf,
    __bf16* __restrict__ wqT, __bf16* __restrict__ woT) {
  int b = blockIdx.x, tid = threadIdx.x;
  if (b < 2304) {
    int i = b * 1024 + tid * 4;
    float4 v = *(const float4*)&x[i];
    bf16x4 o = {(__bf16)v.x, (__bf16)v.y, (__bf16)v.z, (__bf16)v.w};
    *(bf16x4*)&xbf[i] = o;
    return;
  }
  __shared__ float tile[32][33];
  const float* src; __bf16* dst; int R, C, bx, by;
  bool is_wq;
  if (b < 3072) {
    int t = b - 2304; src = wq; dst = wqT; R = 512; C = 1536;
    bx = (t % 48) * 32; by = (t / 48) * 32; is_wq = true;
  } else {
    int t = b - 3072; src = wo; dst = woT; R = 512; C = 512;
    bx = (t & 15) * 32; by = (t >> 4) * 32; is_wq = false;
  }
  int tx = tid & 31, ty = tid >> 5;
#pragma unroll
  for (int i = 0; i < 32; i += 8)
    tile[ty + i][tx] = src[(by + ty + i) * C + bx + tx];
  __syncthreads();
#pragma unroll
  for (int i = 0; i < 32; i += 8) {
    int outrow = bx + ty + i;
    float v = tile[tx][ty + i];
    if (is_wq && outrow < 512) v *= 0.125f;  // fold q/sqrt(D_HEAD) into weights
    dst[outrow * R + by + tx] = (__bf16)v;
  }
}

// ---------------- bf16 MFMA GEMM, BK=64, XOR-swizzled LDS, dbuf gload_lds -----
// C[MxN] = A[MxK] * Bt[NxK]^T. Block tile BM x BN, BK=64 (8 ksteps at K=512 ->
// half the vmcnt(0)+barrier drains vs BK=32). 4 waves (2x2), wave tile BM/2 x BN/2.
// LDS rows are 128B (8 x 16B chunks). Swizzle: LDS[row][c] = G[row][c ^ (row&7)],
// realized by pre-swizzling the per-lane GLOBAL source chunk (gload_lds dest must
// stay linear) and XOR-ing the chunk on the ds_read side (rule #21, both-sides).
// This spreads the 16-lane same-column fragment read over 8 bank-quads (2/quad = free).
// Fragment layouts (verified m89): A[m=lane&15][k=quad*8+j]; Bt same; C/D row=quad*4+r.
template <int BM, int BN>
__global__ __launch_bounds__(256) void gemm_kernel(
    const __bf16* __restrict__ A, const __bf16* __restrict__ Bt,
    void* __restrict__ C, int M, int N, int K, int c_is_f32) {
  constexpr int BK = 64;
  constexpr int MT = BM / 32;      // 16-row m-tiles per wave
  constexpr int NT = BN / 32;      // 16-col n-tiles per wave
  constexpr int NGA = BM / 8;      // 8-row gload groups (1KB each) for A
  constexpr int NGB = BN / 8;
  constexpr int NG = (NGA + NGB) / 4;  // gload calls per wave per stage
  __shared__ __bf16 sA[2][BM * BK];
  __shared__ __bf16 sB[2][BN * BK];
  int tid = threadIdx.x;
  int wv = tid >> 6, lane = tid & 63;
  int quad = lane >> 4, r16 = lane & 15;
  int m0 = blockIdx.y * BM, n0 = blockIdx.x * BN;
  int rl = lane >> 3, cc = lane & 7;
  int csrc = (cc ^ rl) * 8;        // inverse-swizzled source element offset in row

  int mw = (wv & 1) * (BM / 2), nw = (wv >> 1) * (BN / 2);

  f32x4 acc[MT][NT];
#pragma unroll
  for (int mt = 0; mt < MT; ++mt)
#pragma unroll
    for (int nt = 0; nt < NT; ++nt) acc[mt][nt] = f32x4{0.f, 0.f, 0.f, 0.f};

  auto stage = [&](int buf, int k0) {
#pragma unroll
    for (int i = 0; i < NG; ++i) {
      int g = wv + i * 4;
      if (g < NGA) {
        int row = g * 8 + rl;
        gload_lds16(A + (long)(m0 + row) * K + k0 + csrc,
                    (char*)sA[buf] + g * 1024);
      } else {
        int g2 = g - NGA;
        int row = g2 * 8 + rl;
        gload_lds16(Bt + (long)(n0 + row) * K + k0 + csrc,
                    (char*)sB[buf] + g2 * 1024);
      }
    }
  };

  stage(0, 0);
  int cur = 0;
  for (int k0 = 0; k0 < K; k0 += BK) {
    __syncthreads();
    if (k0 + BK < K) stage(cur ^ 1, k0 + BK);
    const char* aB = (const char*)sA[cur];
    const char* bB = (const char*)sB[cur];
    bf16x8 af[2][MT], bfr[2][NT];
#pragma unroll
    for (int ks = 0; ks < 2; ++ks) {
#pragma unroll
      for (int mt = 0; mt < MT; ++mt) {
        int row = mw + mt * 16 + r16;
        af[ks][mt] = *(const bf16x8*)(aB + row * 128 +
                       ((ks * 64 + quad * 16) ^ ((row & 7) << 4)));
      }
#pragma unroll
      for (int nt = 0; nt < NT; ++nt) {
        int row = nw + nt * 16 + r16;
        bfr[ks][nt] = *(const bf16x8*)(bB + row * 128 +
                        ((ks * 64 + quad * 16) ^ ((row & 7) << 4)));
      }
    }
#pragma unroll
    for (int ks = 0; ks < 2; ++ks)
#pragma unroll
      for (int mt = 0; mt < MT; ++mt)
#pragma unroll
        for (int nt = 0; nt < NT; ++nt)
          acc[mt][nt] = __builtin_amdgcn_mfma_f32_16x16x32_bf16(
              af[ks][mt], bfr[ks][nt], acc[mt][nt], 0, 0, 0);
    cur ^= 1;
  }

  __bf16* Cb = (__bf16*)C;
  float* Cf = (float*)C;
#pragma unroll
  for (int mt = 0; mt < MT; ++mt)
#pragma unroll
    for (int r = 0; r < 4; ++r) {
      int row = m0 + mw + mt * 16 + quad * 4 + r;
#pragma unroll
      for (int nt = 0; nt < NT; ++nt) {
        int col = n0 + nw + nt * 16 + r16;
        float v = acc[mt][nt][r];
        if (c_is_f32) Cf[(long)row * N + col] = v;
        else          Cb[(long)row * N + col] = (__bf16)v;
      }
    }
}

// ---------------- neighborhood attention, MFMA over padded 224-pos halo ----------
// Block = 8x8 query tile x 1 head, 4 waves (256 thr). Halo 14x14=196 pos, padded
// to NP=224 (14 n-tiles of 16); invalid (pos,query) pairs masked to -1e30 pre-softmax.
// QK: D[q][pos] = Q[q][k] * K[pos][k]  (A=Q rows, Bt=K rows, both LDS row-major 128B,
//     XOR-swizzled byte^=((row&7)<<4); staged via gload_lds16 w/ pre-swizzled source).
// PV: D[q][ch]  = P[q][pos] * VT[ch][pos] (P reuses dead K buffer; VT is reg-scatter
//     transposed at staging; both 512B rows, same XOR swizzle on write AND read).
// Wave wv owns query m-tile wv for BOTH gemms -> softmax + inv stay lane-local.
__global__ __launch_bounds__(256) void natten_attn_kernel(
    const __bf16* __restrict__ qkv, __bf16* __restrict__ o) {
  __shared__ __bf16 sKP[16384];   // 32KB: K[224 x 128B, swz] -> reused as P[64 x 512B, swz]
  __shared__ __bf16 sVT[16384];   // 32KB: V^T[64ch x 512B, swz]
  __shared__ __bf16 sQ[4096];     // 8KB:  Q[64 x 128B, swz]
  char* kB = (char*)sKP;
  char* vB = (char*)sVT;
  char* qB = (char*)sQ;

  int tid = threadIdx.x;
  int lane = tid & 63, wv = tid >> 6;
  int quad = lane >> 4, r16 = lane & 15;
  int bid = blockIdx.x;                 // 0..575
  int nB = bid / 288;
  int rem = bid - nB * 288;
  int head = rem / 36;
  int tile = rem - head * 36;
  int tr = tile / 6, tc = tile - tr * 6;
  int r0 = tr * 8, c0 = tc * 8;
  int loH = r0 - 3; loH = loH < 0 ? 0 : (loH > 41 ? 41 : loH);
  int loW = c0 - 3; loW = loW < 0 ? 0 : (loW > 41 ? 41 : loW);
  long hb = (long)head * 64;

  // ---- stage K (28 groups of 8 rows) + Q (8 groups) via gload_lds16, pre-swizzled src
  {
    int rl = lane >> 3, cc = lane & 7;   // row-in-group, dest 16B chunk
#pragma unroll
    for (int it = 0; it < 7; ++it) {
      int g = wv * 7 + it;
      int row = g * 8 + rl;
      int pos = row > 195 ? 195 : row;
      int pr = pos / 14, pc = pos - pr * 14;
      int hh = loH + pr; hh = hh > 47 ? 47 : hh;
      int wp = loW + pc; wp = wp > 47 ? 47 : wp;
      int csrc = cc ^ (row & 7);         // inverse-swizzled source chunk
      const __bf16* src = qkv + (long)(nB * 2304 + hh * 48 + wp) * QKV_N + 512 + hb + csrc * 8;
      gload_lds16(src, kB + g * 1024);
    }
#pragma unroll
    for (int it = 0; it < 2; ++it) {
      int g = wv * 2 + it;
      int row = g * 8 + rl;              // query index 0..63
      int csrc = cc ^ (row & 7);
      int pix = nB * 2304 + (r0 + (row >> 3)) * 48 + c0 + (row & 7);
      const __bf16* src = qkv + (long)pix * QKV_N + hb + csrc * 8;
      gload_lds16(src, qB + g * 1024);
    }
  }
  // ---- stage V^T via reg scatter: V[pos][ch] -> sVT[ch][pos], swizzled write
#pragma unroll
  for (int it = 0; it < 7; ++it) {
    int idx = tid + it * 256;            // 0..1791 = 224 pos x 8 chunks
    int pos = idx >> 3, cb = idx & 7;
    int pp = pos > 195 ? 195 : pos;
    int pr = pp / 14, pc = pp - pr * 14;
    int hh = loH + pr; hh = hh > 47 ? 47 : hh;
    int wp = loW + pc; wp = wp > 47 ? 47 : wp;
    bf16x8 v = *(const bf16x8*)(qkv + (long)(nB * 2304 + hh * 48 + wp) * QKV_N + 1024 + hb + cb * 8);
#pragma unroll
    for (int i = 0; i < 8; ++i) {
      int ch = cb * 8 + i;
      *(__bf16*)(vB + ch * 512 + ((2 * pos) ^ ((ch & 7) << 4))) = v[i];
    }
  }
  __syncthreads();

  // ---- QK^T: wave wv = query m-tile wv x 14 pos n-tiles, K=64 (2 ksteps)
  int rowq = wv * 16 + r16;
  int swq = (rowq & 7) << 4;
  bf16x8 aq0 = *(const bf16x8*)(qB + rowq * 128 + ((quad * 16) ^ swq));
  bf16x8 aq1 = *(const bf16x8*)(qB + rowq * 128 + ((64 + quad * 16) ^ swq));
  f32x4 acc[14];
#pragma unroll
  for (int nt = 0; nt < 14; ++nt) acc[nt] = f32x4{0.f, 0.f, 0.f, 0.f};
#pragma unroll
  for (int nt = 0; nt < 14; ++nt) {
    int rk = nt * 16 + r16;
    int swk = (rk & 7) << 4;
    bf16x8 b0 = *(const bf16x8*)(kB + rk * 128 + ((quad * 16) ^ swk));
    bf16x8 b1 = *(const bf16x8*)(kB + rk * 128 + ((64 + quad * 16) ^ swk));
    acc[nt] = __builtin_amdgcn_mfma_f32_16x16x32_bf16(aq0, b0, acc[nt], 0, 0, 0);
    acc[nt] = __builtin_amdgcn_mfma_f32_16x16x32_bf16(aq1, b1, acc[nt], 0, 0, 0);
  }

  // ---- mask + softmax. Lane holds queries quad*4+r (r=0..3), positions nt*16+r16.
  int hs[4], wsX[4];
#pragma unroll
  for (int r = 0; r < 4; ++r) {
    int q = wv * 16 + quad * 4 + r;
    int h = r0 + (q >> 3), w = c0 + (q & 7);
    int a = h - 3; a = a < 0 ? 0 : (a > 41 ? 41 : a);
    int b = w - 3; b = b < 0 ? 0 : (b > 41 ? 41 : b);
    hs[r] = a - loH; wsX[r] = b - loW;
  }
  {
    int pr = r16 >= 14 ? 1 : 0;
    int pc = r16 - pr * 14;
#pragma unroll
    for (int nt = 0; nt < 14; ++nt) {
      bool pv = (nt * 16 + r16) < 196;
#pragma unroll
      for (int r = 0; r < 4; ++r) {
        bool ok = pv && (unsigned)(pr - hs[r]) <= 6u && (unsigned)(pc - wsX[r]) <= 6u;
        acc[nt][r] = ok ? acc[nt][r] : -1e30f;
      }
      pc += 2; pr += 1;                 // pos += 16 == (+1 row, +2 cols) in 14-wide halo
      if (pc >= 14) { pc -= 14; pr += 1; }
    }
  }
  float inv[4];
#pragma unroll
  for (int r = 0; r < 4; ++r) {
    float m = acc[0][r];
#pragma unroll
    for (int nt = 1; nt < 14; ++nt) m = fmaxf(m, acc[nt][r]);
    m = fmaxf(m, __shfl_xor(m, 1));
    m = fmaxf(m, __shfl_xor(m, 2));
    m = fmaxf(m, __shfl_xor(m, 4));
    m = fmaxf(m, __shfl_xor(m, 8));
    float s = 0.f;
#pragma unroll
    for (int nt = 0; nt < 14; ++nt) { float e = __expf(acc[nt][r] - m); acc[nt][r] = e; s += e; }
    s += __shfl_xor(s, 1);
    s += __shfl_xor(s, 2);
    s += __shfl_xor(s, 4);
    s += __shfl_xor(s, 8);
    inv[r] = 1.f / s;
  }
  __syncthreads();   // all waves done reading sKP before it becomes P

  // ---- write P (bf16, unnormalized) into sKP as [64 q][512B, swz]
#pragma unroll
  for (int r = 0; r < 4; ++r) {
    int q = wv * 16 + quad * 4 + r;
    char* rowp = kB + q * 512;
    int sw = (q & 7) << 4;
#pragma unroll
    for (int nt = 0; nt < 14; ++nt) {
      int pos = nt * 16 + r16;
      *(__bf16*)(rowp + ((2 * pos) ^ sw)) = (__bf16)acc[nt][r];
    }
  }
  __syncthreads();

  // ---- PV: wave wv = query m-tile wv x 4 ch n-tiles, K=224 (7 ksteps)
  f32x4 acc2[4];
#pragma unroll
  for (int nt = 0; nt < 4; ++nt) acc2[nt] = f32x4{0.f, 0.f, 0.f, 0.f};
#pragma unroll
  for (int ks = 0; ks < 7; ++ks) {
    bf16x8 ap = *(const bf16x8*)(kB + rowq * 512 + ((ks * 64 + quad * 16) ^ swq));
#pragma unroll
    for (int nt = 0; nt < 4; ++nt) {
      int rc = nt * 16 + r16;
      bf16x8 bv = *(const bf16x8*)(vB + rc * 512 + ((ks * 64 + quad * 16) ^ ((rc & 7) << 4)));
      acc2[nt] = __builtin_amdgcn_mfma_f32_16x16x32_bf16(ap, bv, acc2[nt], 0, 0, 0);
    }
  }

  // ---- epilogue: normalize and store
#pragma unroll
  for (int r = 0; r < 4; ++r) {
    int q = wv * 16 + quad * 4 + r;
    long pix = nB * 2304 + (long)(r0 + (q >> 3)) * 48 + c0 + (q & 7);
    __bf16* op = o + pix * D_MODEL + hb;
    float iv = inv[r];
#pragma unroll
    for (int nt = 0; nt < 4; ++nt)
      op[nt * 16 + r16] = (__bf16)(acc2[nt][r] * iv);
  }
}

// ---------------- launch ----------------

extern "C" void kernel_launch(void* const* d_in, const int* in_sizes, int n_in,
                              void* d_out, int out_size, void* d_ws, size_t ws_size,
                              hipStream_t stream) {
  const float* x = (const float*)d_in[0];      // (2,48,48,512)
  const float* w_qkv = (const float*)d_in[1];  // (512,1536)
  const float* w_out = (const float*)d_in[2];  // (512,512)
  float* out = (float*)d_out;                  // (2,48,48,512)

  __bf16* ws = (__bf16*)d_ws;
  __bf16* xbf   = ws;                                   // 4608*512
  __bf16* wqkvT = xbf + N_PIX * D_MODEL;                // 1536*512
  __bf16* woutT = wqkvT + QKV_N * D_MODEL;              // 512*512
  __bf16* qkvb  = woutT + D_MODEL * D_MODEL;            // 4608*1536
  __bf16* obf   = qkvb + N_PIX * QKV_N;                 // 4608*512

  // prep: x->bf16 (2304 blocks) + w_qkv^T scaled (768) + w_out^T (256)
  prep_kernel<<<3328, 256, 0, stream>>>(x, w_qkv, w_out, xbf, wqkvT, woutT);
  // qkv = xbf @ w_qkv -> bf16 (4608 x 1536); 64x128xBK64 -> 12x72=864 blocks, 8 drains
  gemm_kernel<64, 128><<<dim3(QKV_N / 128, N_PIX / 64), 256, 0, stream>>>(
      xbf, wqkvT, qkvb, N_PIX, QKV_N, D_MODEL, 0);
  // attention -> obf (4608 x 512), MFMA formulation
  natten_attn_kernel<<<576, 256, 0, stream>>>(qkvb, obf);
  // out = obf @ w_out -> fp32; 64x64xBK64 -> 8x72=576 blocks, 8 drains
  gemm_kernel<64, 64><<<dim3(D_MODEL / 64, N_PIX / 64), 256, 0, stream>>>(
      obf, woutT, out, N_PIX, D_MODEL, D_MODEL, 1);
}

// Round 4
// 111.119 us; speedup vs baseline: 1.0970x; 1.0080x over previous
//
#include <hip/hip_runtime.h>
#include <hip/hip_bf16.h>

typedef __bf16 bf16x4 __attribute__((ext_vector_type(4)));
typedef __bf16 bf16x8 __attribute__((ext_vector_type(8)));
typedef float f32x4 __attribute__((ext_vector_type(4)));

#define N_PIX 4608      // 2*48*48
#define D_MODEL 512
#define QKV_N 1536

// async global->LDS, 16B per lane. LDS dest is wave-uniform base; HW adds lane*16.
__device__ __forceinline__ void gload_lds16(const void* g, void* l) {
  __builtin_amdgcn_global_load_lds(
      (const __attribute__((address_space(1))) unsigned int*)g,
      (__attribute__((address_space(3))) unsigned int*)l, 16, 0, 0);
}

// ---------------- fused prep: x->bf16 + both weight transposes ----------------
// blocks [0,2304): x convert; [2304,3072): w_qkv^T (q-scale folded); [3072,3328): w_out^T
__global__ __launch_bounds__(256) void prep_kernel(
    const float* __restrict__ x, const float* __restrict__ wq,
    const float* __restrict__ wo, __bf16* __restrict__ xbf,
    __bf16* __restrict__ wqT, __bf16* __restrict__ woT) {
  int b = blockIdx.x, tid = threadIdx.x;
  if (b < 2304) {
    int i = b * 1024 + tid * 4;
    float4 v = *(const float4*)&x[i];
    bf16x4 o = {(__bf16)v.x, (__bf16)v.y, (__bf16)v.z, (__bf16)v.w};
    *(bf16x4*)&xbf[i] = o;
    return;
  }
  __shared__ float tile[32][33];
  const float* src; __bf16* dst; int R, C, bx, by;
  bool is_wq;
  if (b < 3072) {
    int t = b - 2304; src = wq; dst = wqT; R = 512; C = 1536;
    bx = (t % 48) * 32; by = (t / 48) * 32; is_wq = true;
  } else {
    int t = b - 3072; src = wo; dst = woT; R = 512; C = 512;
    bx = (t & 15) * 32; by = (t >> 4) * 32; is_wq = false;
  }
  int tx = tid & 31, ty = tid >> 5;
#pragma unroll
  for (int i = 0; i < 32; i += 8)
    tile[ty + i][tx] = src[(by + ty + i) * C + bx + tx];
  __syncthreads();
#pragma unroll
  for (int i = 0; i < 32; i += 8) {
    int outrow = bx + ty + i;
    float v = tile[tx][ty + i];
    if (is_wq && outrow < 512) v *= 0.125f;  // fold q/sqrt(D_HEAD) into weights
    dst[outrow * R + by + tx] = (__bf16)v;
  }
}

// ---------------- bf16 MFMA GEMM, BK=64, swizzled LDS, counted-vmcnt pipeline --
// C[MxN] = A[MxK] * Bt[NxK]^T. BK=64, 4 waves (2x2), wave tile BM/2 x BN/2.
// Depth-2 prefetch, T4 counted vmcnt (m218): per iter wait vmcnt(NG) -- only tile
// t's NG gload_lds drained; tile t+1's stay in flight ACROSS the raw s_barrier.
// Hazards: (1) per-wave vmcnt(NG)+barrier => all waves' t-loads landed before any
// ds_read; (2) lgkmcnt(0)+sched_barrier(0) [rule #18] + barrier => all frags in
// regs before stage(t+2) overwrites buf[t&1]; (3) tail waits vmcnt(0).
// LDS swizzle (rule #21 both-sides): inverse-swizzled GLOBAL source chunk at
// stage, XOR'd chunk on ds_read: LDS[row][c] = G[row][c ^ (row&7)].
template <int BM, int BN>
__global__ __launch_bounds__(256) void gemm_kernel(
    const __bf16* __restrict__ A, const __bf16* __restrict__ Bt,
    void* __restrict__ C, int M, int N, int K, int c_is_f32) {
  constexpr int BK = 64;
  constexpr int MT = BM / 32;      // 16-row m-tiles per wave
  constexpr int NT = BN / 32;      // 16-col n-tiles per wave
  constexpr int NGA = BM / 8;      // 8-row gload groups (1KB each) for A
  constexpr int NGB = BN / 8;
  constexpr int NG = (NGA + NGB) / 4;  // gload calls per wave per stage (6 or 4)
  __shared__ __bf16 sA[2][BM * BK];
  __shared__ __bf16 sB[2][BN * BK];
  int tid = threadIdx.x;
  int wv = tid >> 6, lane = tid & 63;
  int quad = lane >> 4, r16 = lane & 15;
  int m0 = blockIdx.y * BM, n0 = blockIdx.x * BN;
  int rl = lane >> 3, cc = lane & 7;
  int csrc = (cc ^ rl) * 8;        // inverse-swizzled source element offset in row

  int mw = (wv & 1) * (BM / 2), nw = (wv >> 1) * (BN / 2);

  f32x4 acc[MT][NT];
#pragma unroll
  for (int mt = 0; mt < MT; ++mt)
#pragma unroll
    for (int nt = 0; nt < NT; ++nt) acc[mt][nt] = f32x4{0.f, 0.f, 0.f, 0.f};

  auto stage = [&](int buf, int k0) {
#pragma unroll
    for (int i = 0; i < NG; ++i) {
      int g = wv + i * 4;
      if (g < NGA) {
        int row = g * 8 + rl;
        gload_lds16(A + (long)(m0 + row) * K + k0 + csrc,
                    (char*)sA[buf] + g * 1024);
      } else {
        int g2 = g - NGA;
        int row = g2 * 8 + rl;
        gload_lds16(Bt + (long)(n0 + row) * K + k0 + csrc,
                    (char*)sB[buf] + g2 * 1024);
      }
    }
  };

  int ntile = K >> 6;              // 8 at K=512
  stage(0, 0);
  if (ntile > 1) stage(1, BK);
  for (int t = 0; t < ntile; ++t) {
    // ---- barrier 1: tile t's loads (issued 2 iters ago) complete wave-wide;
    //      tile t+1's NG loads stay in flight (counted vmcnt).
    if (t < ntile - 1) {
      if constexpr (NG == 4) asm volatile("s_waitcnt vmcnt(4)" ::: "memory");
      else                   asm volatile("s_waitcnt vmcnt(6)" ::: "memory");
    } else {
      asm volatile("s_waitcnt vmcnt(0)" ::: "memory");
    }
    __builtin_amdgcn_s_barrier();

    const char* aB = (const char*)sA[t & 1];
    const char* bB = (const char*)sB[t & 1];
    bf16x8 af[2][MT], bfr[2][NT];
#pragma unroll
    for (int ks = 0; ks < 2; ++ks) {
#pragma unroll
      for (int mt = 0; mt < MT; ++mt) {
        int row = mw + mt * 16 + r16;
        af[ks][mt] = *(const bf16x8*)(aB + row * 128 +
                       ((ks * 64 + quad * 16) ^ ((row & 7) << 4)));
      }
#pragma unroll
      for (int nt = 0; nt < NT; ++nt) {
        int row = nw + nt * 16 + r16;
        bfr[ks][nt] = *(const bf16x8*)(bB + row * 128 +
                        ((ks * 64 + quad * 16) ^ ((row & 7) << 4)));
      }
    }
    // ---- barrier 2: all fragment reads in regs before buf[t&1] is overwritten.
    asm volatile("s_waitcnt lgkmcnt(0)" ::: "memory");
    __builtin_amdgcn_sched_barrier(0);
    __builtin_amdgcn_s_barrier();
    if (t + 2 < ntile) stage(t & 1, (t + 2) << 6);

#pragma unroll
    for (int ks = 0; ks < 2; ++ks)
#pragma unroll
      for (int mt = 0; mt < MT; ++mt)
#pragma unroll
        for (int nt = 0; nt < NT; ++nt)
          acc[mt][nt] = __builtin_amdgcn_mfma_f32_16x16x32_bf16(
              af[ks][mt], bfr[ks][nt], acc[mt][nt], 0, 0, 0);
  }

  __bf16* Cb = (__bf16*)C;
  float* Cf = (float*)C;
#pragma unroll
  for (int mt = 0; mt < MT; ++mt)
#pragma unroll
    for (int r = 0; r < 4; ++r) {
      int row = m0 + mw + mt * 16 + quad * 4 + r;
#pragma unroll
      for (int nt = 0; nt < NT; ++nt) {
        int col = n0 + nw + nt * 16 + r16;
        float v = acc[mt][nt][r];
        if (c_is_f32) Cf[(long)row * N + col] = v;
        else          Cb[(long)row * N + col] = (__bf16)v;
      }
    }
}

// ---------------- neighborhood attention, MFMA over padded 224-pos halo ----------
// Block = 8x8 query tile x 1 head, 4 waves (256 thr). Halo 14x14=196 pos, padded
// to NP=224 (14 n-tiles of 16); invalid (pos,query) pairs masked to -1e30 pre-softmax.
// QK: D[q][pos] = Q[q][k] * K[pos][k]  (A=Q rows, Bt=K rows, both LDS row-major 128B,
//     XOR-swizzled byte^=((row&7)<<4); staged via gload_lds16 w/ pre-swizzled source).
// PV: D[q][ch]  = P[q][pos] * VT[ch][pos] (P reuses dead K buffer; VT is reg-scatter
//     transposed at staging; both 512B rows, same XOR swizzle on write AND read).
// Wave wv owns query m-tile wv for BOTH gemms -> softmax + inv stay lane-local.
__global__ __launch_bounds__(256) void natten_attn_kernel(
    const __bf16* __restrict__ qkv, __bf16* __restrict__ o) {
  __shared__ __bf16 sKP[16384];   // 32KB: K[224 x 128B, swz] -> reused as P[64 x 512B, swz]
  __shared__ __bf16 sVT[16384];   // 32KB: V^T[64ch x 512B, swz]
  __shared__ __bf16 sQ[4096];     // 8KB:  Q[64 x 128B, swz]
  char* kB = (char*)sKP;
  char* vB = (char*)sVT;
  char* qB = (char*)sQ;

  int tid = threadIdx.x;
  int lane = tid & 63, wv = tid >> 6;
  int quad = lane >> 4, r16 = lane & 15;
  int bid = blockIdx.x;                 // 0..575
  int nB = bid / 288;
  int rem = bid - nB * 288;
  int head = rem / 36;
  int tile = rem - head * 36;
  int tr = tile / 6, tc = tile - tr * 6;
  int r0 = tr * 8, c0 = tc * 8;
  int loH = r0 - 3; loH = loH < 0 ? 0 : (loH > 41 ? 41 : loH);
  int loW = c0 - 3; loW = loW < 0 ? 0 : (loW > 41 ? 41 : loW);
  long hb = (long)head * 64;

  // ---- stage K (28 groups of 8 rows) + Q (8 groups) via gload_lds16, pre-swizzled src
  {
    int rl = lane >> 3, cc = lane & 7;   // row-in-group, dest 16B chunk
#pragma unroll
    for (int it = 0; it < 7; ++it) {
      int g = wv * 7 + it;
      int row = g * 8 + rl;
      int pos = row > 195 ? 195 : row;
      int pr = pos / 14, pc = pos - pr * 14;
      int hh = loH + pr; hh = hh > 47 ? 47 : hh;
      int wp = loW + pc; wp = wp > 47 ? 47 : wp;
      int csrc = cc ^ (row & 7);         // inverse-swizzled source chunk
      const __bf16* src = qkv + (long)(nB * 2304 + hh * 48 + wp) * QKV_N + 512 + hb + csrc * 8;
      gload_lds16(src, kB + g * 1024);
    }
#pragma unroll
    for (int it = 0; it < 2; ++it) {
      int g = wv * 2 + it;
      int row = g * 8 + rl;              // query index 0..63
      int csrc = cc ^ (row & 7);
      int pix = nB * 2304 + (r0 + (row >> 3)) * 48 + c0 + (row & 7);
      const __bf16* src = qkv + (long)pix * QKV_N + hb + csrc * 8;
      gload_lds16(src, qB + g * 1024);
    }
  }
  // ---- stage V^T via reg scatter: V[pos][ch] -> sVT[ch][pos], swizzled write
#pragma unroll
  for (int it = 0; it < 7; ++it) {
    int idx = tid + it * 256;            // 0..1791 = 224 pos x 8 chunks
    int pos = idx >> 3, cb = idx & 7;
    int pp = pos > 195 ? 195 : pos;
    int pr = pp / 14, pc = pp - pr * 14;
    int hh = loH + pr; hh = hh > 47 ? 47 : hh;
    int wp = loW + pc; wp = wp > 47 ? 47 : wp;
    bf16x8 v = *(const bf16x8*)(qkv + (long)(nB * 2304 + hh * 48 + wp) * QKV_N + 1024 + hb + cb * 8);
#pragma unroll
    for (int i = 0; i < 8; ++i) {
      int ch = cb * 8 + i;
      *(__bf16*)(vB + ch * 512 + ((2 * pos) ^ ((ch & 7) << 4))) = v[i];
    }
  }
  __syncthreads();

  // ---- QK^T: wave wv = query m-tile wv x 14 pos n-tiles, K=64 (2 ksteps)
  int rowq = wv * 16 + r16;
  int swq = (rowq & 7) << 4;
  bf16x8 aq0 = *(const bf16x8*)(qB + rowq * 128 + ((quad * 16) ^ swq));
  bf16x8 aq1 = *(const bf16x8*)(qB + rowq * 128 + ((64 + quad * 16) ^ swq));
  f32x4 acc[14];
#pragma unroll
  for (int nt = 0; nt < 14; ++nt) acc[nt] = f32x4{0.f, 0.f, 0.f, 0.f};
#pragma unroll
  for (int nt = 0; nt < 14; ++nt) {
    int rk = nt * 16 + r16;
    int swk = (rk & 7) << 4;
    bf16x8 b0 = *(const bf16x8*)(kB + rk * 128 + ((quad * 16) ^ swk));
    bf16x8 b1 = *(const bf16x8*)(kB + rk * 128 + ((64 + quad * 16) ^ swk));
    acc[nt] = __builtin_amdgcn_mfma_f32_16x16x32_bf16(aq0, b0, acc[nt], 0, 0, 0);
    acc[nt] = __builtin_amdgcn_mfma_f32_16x16x32_bf16(aq1, b1, acc[nt], 0, 0, 0);
  }

  // ---- mask + softmax. Lane holds queries quad*4+r (r=0..3), positions nt*16+r16.
  int hs[4], wsX[4];
#pragma unroll
  for (int r = 0; r < 4; ++r) {
    int q = wv * 16 + quad * 4 + r;
    int h = r0 + (q >> 3), w = c0 + (q & 7);
    int a = h - 3; a = a < 0 ? 0 : (a > 41 ? 41 : a);
    int b = w - 3; b = b < 0 ? 0 : (b > 41 ? 41 : b);
    hs[r] = a - loH; wsX[r] = b - loW;
  }
  {
    int pr = r16 >= 14 ? 1 : 0;
    int pc = r16 - pr * 14;
#pragma unroll
    for (int nt = 0; nt < 14; ++nt) {
      bool pv = (nt * 16 + r16) < 196;
#pragma unroll
      for (int r = 0; r < 4; ++r) {
        bool ok = pv && (unsigned)(pr - hs[r]) <= 6u && (unsigned)(pc - wsX[r]) <= 6u;
        acc[nt][r] = ok ? acc[nt][r] : -1e30f;
      }
      pc += 2; pr += 1;                 // pos += 16 == (+1 row, +2 cols) in 14-wide halo
      if (pc >= 14) { pc -= 14; pr += 1; }
    }
  }
  float inv[4];
#pragma unroll
  for (int r = 0; r < 4; ++r) {
    float m = acc[0][r];
#pragma unroll
    for (int nt = 1; nt < 14; ++nt) m = fmaxf(m, acc[nt][r]);
    m = fmaxf(m, __shfl_xor(m, 1));
    m = fmaxf(m, __shfl_xor(m, 2));
    m = fmaxf(m, __shfl_xor(m, 4));
    m = fmaxf(m, __shfl_xor(m, 8));
    float s = 0.f;
#pragma unroll
    for (int nt = 0; nt < 14; ++nt) { float e = __expf(acc[nt][r] - m); acc[nt][r] = e; s += e; }
    s += __shfl_xor(s, 1);
    s += __shfl_xor(s, 2);
    s += __shfl_xor(s, 4);
    s += __shfl_xor(s, 8);
    inv[r] = 1.f / s;
  }
  __syncthreads();   // all waves done reading sKP before it becomes P

  // ---- write P (bf16, unnormalized) into sKP as [64 q][512B, swz]
#pragma unroll
  for (int r = 0; r < 4; ++r) {
    int q = wv * 16 + quad * 4 + r;
    char* rowp = kB + q * 512;
    int sw = (q & 7) << 4;
#pragma unroll
    for (int nt = 0; nt < 14; ++nt) {
      int pos = nt * 16 + r16;
      *(__bf16*)(rowp + ((2 * pos) ^ sw)) = (__bf16)acc[nt][r];
    }
  }
  __syncthreads();

  // ---- PV: wave wv = query m-tile wv x 4 ch n-tiles, K=224 (7 ksteps)
  f32x4 acc2[4];
#pragma unroll
  for (int nt = 0; nt < 4; ++nt) acc2[nt] = f32x4{0.f, 0.f, 0.f, 0.f};
#pragma unroll
  for (int ks = 0; ks < 7; ++ks) {
    bf16x8 ap = *(const bf16x8*)(kB + rowq * 512 + ((ks * 64 + quad * 16) ^ swq));
#pragma unroll
    for (int nt = 0; nt < 4; ++nt) {
      int rc = nt * 16 + r16;
      bf16x8 bv = *(const bf16x8*)(vB + rc * 512 + ((ks * 64 + quad * 16) ^ ((rc & 7) << 4)));
      acc2[nt] = __builtin_amdgcn_mfma_f32_16x16x32_bf16(ap, bv, acc2[nt], 0, 0, 0);
    }
  }

  // ---- epilogue: normalize and store
#pragma unroll
  for (int r = 0; r < 4; ++r) {
    int q = wv * 16 + quad * 4 + r;
    long pix = nB * 2304 + (long)(r0 + (q >> 3)) * 48 + c0 + (q & 7);
    __bf16* op = o + pix * D_MODEL + hb;
    float iv = inv[r];
#pragma unroll
    for (int nt = 0; nt < 4; ++nt)
      op[nt * 16 + r16] = (__bf16)(acc2[nt][r] * iv);
  }
}

// ---------------- launch ----------------

extern "C" void kernel_launch(void* const* d_in, const int* in_sizes, int n_in,
                              void* d_out, int out_size, void* d_ws, size_t ws_size,
                              hipStream_t stream) {
  const float* x = (const float*)d_in[0];      // (2,48,48,512)
  const float* w_qkv = (const float*)d_in[1];  // (512,1536)
  const float* w_out = (const float*)d_in[2];  // (512,512)
  float* out = (float*)d_out;                  // (2,48,48,512)

  __bf16* ws = (__bf16*)d_ws;
  __bf16* xbf   = ws;                                   // 4608*512
  __bf16* wqkvT = xbf + N_PIX * D_MODEL;                // 1536*512
  __bf16* woutT = wqkvT + QKV_N * D_MODEL;              // 512*512
  __bf16* qkvb  = woutT + D_MODEL * D_MODEL;            // 4608*1536
  __bf16* obf   = qkvb + N_PIX * QKV_N;                 // 4608*512

  // prep: x->bf16 (2304 blocks) + w_qkv^T scaled (768) + w_out^T (256)
  prep_kernel<<<3328, 256, 0, stream>>>(x, w_qkv, w_out, xbf, wqkvT, woutT);
  // qkv = xbf @ w_qkv -> bf16 (4608 x 1536); 64x128xBK64, counted-vmcnt pipeline
  gemm_kernel<64, 128><<<dim3(QKV_N / 128, N_PIX / 64), 256, 0, stream>>>(
      xbf, wqkvT, qkvb, N_PIX, QKV_N, D_MODEL, 0);
  // attention -> obf (4608 x 512), MFMA formulation
  natten_attn_kernel<<<576, 256, 0, stream>>>(qkvb, obf);
  // out = obf @ w_out -> fp32; 64x64xBK64, counted-vmcnt pipeline
  gemm_kernel<64, 64><<<dim3(D_MODEL / 64, N_PIX / 64), 256, 0, stream>>>(
      obf, woutT, out, N_PIX, D_MODEL, D_MODEL, 1);
}